// Round 11
// baseline (117.865 us; speedup 1.0000x reference)
//
#include <hip/hip_runtime.h>

// CIN (xDeepFM) fused kernel for MI355X (gfx950), round 11.
// L0 z-operands from REGISTERS: K re-indexed as s=nbi*10+mg with n=nbi*8+j
// (xn chunk = xreg[nt][nbi], static under unroll), m=mg*4+lhi (xm = 2 scalar
// u16 LDS reads/step, prefetched 1 ahead). Waves = 64 rows x 32 cols so the
// per-lane x-vector (2 cols x 5 f16x8 = 40 VGPR) fits. L0 K-loop: 2 LDS ops,
// ~10 VALU, 8 MFMA, 4 global b128 (2-deep prefetch), zero barriers.
// L1 verbatim r7 (reassociated, hf persistent, 4rt x 2kh, xmv 1-ahead).
// 512 thr x 512 blocks, 2 blocks/CU.

typedef _Float16 f16x8 __attribute__((ext_vector_type(8)));
typedef float f32x4 __attribute__((ext_vector_type(4)));

#define NB 2
#define NBLK 512
#define THREADS 512
#define K0P 52   // padded L0 steps (s=50,51 zero) for prefetch overrun
#define M1P 42

__global__ __launch_bounds__(256) void prep_kernel(
    const float* __restrict__ w0, const float* __restrict__ w1,
    _Float16* __restrict__ w0n, _Float16* __restrict__ w1c) {
  int stride = gridDim.x * blockDim.x;
  int tid = blockIdx.x * blockDim.x + threadIdx.x;
  // w0n: [s<52][rg<4][mt<4][l15<16][lhi<4][j<8]; o = rg*64+mt*16+l15;
  //      s<50: m = (s%10)*4+lhi, n = (s/10)*8+j; zero outside m<39,n<39.
  const int n0 = K0P * 8192;
  for (int idx = tid; idx < n0; idx += stride) {
    int j = idx & 7, lhi = (idx >> 3) & 3, l15 = (idx >> 5) & 15;
    int mt = (idx >> 9) & 3, rg = (idx >> 11) & 3, s = idx >> 13;
    int o = rg * 64 + mt * 16 + l15;
    float v = 0.f;
    if (s < 50) {
      int nbi = s / 10, mg = s - nbi * 10;
      int m = mg * 4 + lhi, n = nbi * 8 + j;
      if (m < 39 && n < 39) v = w0[o * 1521 + m * 39 + n];
    }
    w0n[idx] = (_Float16)v;
  }
  // w1c: [m<42][kh<2][rt<4][kf<2][mt<2][l15<16][lhi<4][j<8];
  //      row o=rt*32+mt*16+l15, k = kh*64+kf*32+lhi*8+j (within W1_m).
  const int n1 = M1P * 16384;
  for (int idx = tid; idx < n1; idx += stride) {
    int j = idx & 7, lhi = (idx >> 3) & 3, l15 = (idx >> 5) & 15;
    int mt = (idx >> 9) & 1, kf = (idx >> 10) & 1, rt = (idx >> 11) & 3;
    int kh = (idx >> 13) & 1, m = idx >> 14;
    int o = rt * 32 + mt * 16 + l15;
    int k = kh * 64 + kf * 32 + lhi * 8 + j;
    float v = (m < 39) ? w1[o * 4992 + m * 128 + k] : 0.f;
    w1c[idx] = (_Float16)v;
  }
}

__global__ __launch_bounds__(512, 2) void cin_kernel(
    const float* __restrict__ x,
    const _Float16* __restrict__ w0n, const float* __restrict__ b0,
    const _Float16* __restrict__ w1c, const float* __restrict__ b1,
    float* __restrict__ out) {
  // LDS: 5120 + 17408 + 33280 = 55808 B -> 2 blocks/CU
  __shared__ __align__(16) _Float16 xs[NB * 32 * 40];  // [c=(b,d)][40], col 39 = 0
  __shared__ __align__(16) _Float16 h1[64 * 136];      // [c][136] h1a
  __shared__ __align__(16) float red[4 * 32 * 65];     // K-half exchange

  const int t = threadIdx.x;
  const int bb = blockIdx.x * NB;
  const int w = t >> 6;          // wave 0..7
  const int l15 = t & 15;
  const int lhi = (t >> 4) & 3;
  const int lane_off = l15 * 32 + lhi * 8;

  // ---- stage x -> xs[c][m], f16 ----
  for (int idx = t; idx < NB * 39 * 32; idx += THREADS) {
    int b = idx / 1248; int rem = idx - b * 1248;
    int m = rem >> 5; int d = rem & 31;
    xs[(b * 32 + d) * 40 + m] = (_Float16)x[(bb + b) * 1248 + rem];
  }
  if (t < NB * 32) xs[t * 40 + 39] = (_Float16)0.f;  // zero pad slot 39
  __syncthreads();

  // ================= LAYER 0: 64 rows x 32 cols per wave =================
  const int rg = w >> 1, cg = w & 1;
  const int xc0 = (cg * 32 + l15) * 40;        // col base, nt=0
  const int xc1 = (cg * 32 + 16 + l15) * 40;   // col base, nt=1

  f16x8 xreg[2][5];
#pragma unroll
  for (int q = 0; q < 5; ++q) {
    xreg[0][q] = *(const f16x8*)&xs[xc0 + q * 8];
    xreg[1][q] = *(const f16x8*)&xs[xc1 + q * 8];
  }

  f32x4 acc[4][2] = {};
  const _Float16* p0 = w0n + rg * 2048 + lane_off;
  f16x8 af[2][4];
  auto loadA0 = [&](int s, int b) {
    const _Float16* p = p0 + s * 8192;
#pragma unroll
    for (int mt = 0; mt < 4; ++mt) af[b][mt] = *(const f16x8*)(p + mt * 512);
  };
  _Float16 xmr[2][2];
  auto xmld = [&](int mg4, int b) {   // mg4 = (s%10)*4; m = mg4 + lhi
    xmr[b][0] = xs[xc0 + mg4 + lhi];
    xmr[b][1] = xs[xc1 + mg4 + lhi];
  };

  loadA0(0, 0); loadA0(1, 1);
  xmld(0, 0);
#pragma unroll
  for (int nbi = 0; nbi < 5; ++nbi) {      // xreg[.][nbi] must be static
    for (int mg2 = 0; mg2 < 5; ++mg2) {    // 2 steps per iteration
      const int s = nbi * 10 + mg2 * 2;
      xmld((mg2 * 2 + 1) * 4, 1);          // prefetch xm for step s+1
      {
        f16x8 bz0 = xreg[0][nbi] * xmr[0][0];
        f16x8 bz1 = xreg[1][nbi] * xmr[0][1];
#pragma unroll
        for (int mt = 0; mt < 4; ++mt) {
          acc[mt][0] = __builtin_amdgcn_mfma_f32_16x16x32_f16(af[0][mt], bz0, acc[mt][0], 0, 0, 0);
          acc[mt][1] = __builtin_amdgcn_mfma_f32_16x16x32_f16(af[0][mt], bz1, acc[mt][1], 0, 0, 0);
        }
      }
      loadA0(s + 2, 0);
      if (s + 2 < 50) xmld(mg2 < 4 ? (mg2 * 2 + 2) * 4 : 0, 0);  // xm for s+2
      {
        f16x8 bz0 = xreg[0][nbi] * xmr[1][0];
        f16x8 bz1 = xreg[1][nbi] * xmr[1][1];
#pragma unroll
        for (int mt = 0; mt < 4; ++mt) {
          acc[mt][0] = __builtin_amdgcn_mfma_f32_16x16x32_f16(af[1][mt], bz0, acc[mt][0], 0, 0, 0);
          acc[mt][1] = __builtin_amdgcn_mfma_f32_16x16x32_f16(af[1][mt], bz1, acc[mt][1], 0, 0, 0);
        }
      }
      loadA0(s + 3, 1);                    // max 51 < K0P
    }
  }

  // ---- epilogue 0: bias+relu; o<128 -> h1; o>=128 -> d-sum -> out[0..127] ----
  if (rg < 2) {
#pragma unroll
    for (int mt = 0; mt < 4; ++mt)
#pragma unroll
      for (int nt = 0; nt < 2; ++nt) {
        int c = cg * 32 + nt * 16 + l15;
#pragma unroll
        for (int r = 0; r < 4; ++r) {
          int o = rg * 64 + mt * 16 + lhi * 4 + r;
          float v = fmaxf(acc[mt][nt][r] + b0[o], 0.f);
          h1[c * 136 + o] = (_Float16)v;
        }
      }
  } else {
#pragma unroll
    for (int mt = 0; mt < 4; ++mt)
#pragma unroll
      for (int r = 0; r < 4; ++r) {
        int o = rg * 64 + mt * 16 + lhi * 4 + r;  // 128..255
        float bias = b0[o];
        float v = fmaxf(acc[mt][0][r] + bias, 0.f) + fmaxf(acc[mt][1][r] + bias, 0.f);
        v += __shfl_xor(v, 1); v += __shfl_xor(v, 2);
        v += __shfl_xor(v, 4); v += __shfl_xor(v, 8);
        if (l15 == 0) out[(bb + cg) * 256 + (o - 128)] = v;
      }
  }
  __syncthreads();  // h1 visible

  // ============ LAYER 1 (r7 verbatim: 4 row-groups x 2 K-halves) ============
  const int rt = w >> 1;
  const int kh = w & 1;
  int xrow4[4];
#pragma unroll
  for (int nt = 0; nt < 4; ++nt) xrow4[nt] = (nt * 16 + l15) * 40;

  f16x8 hf[2][4];
#pragma unroll
  for (int kf = 0; kf < 2; ++kf)
#pragma unroll
    for (int nt = 0; nt < 4; ++nt)
      hf[kf][nt] = *(const f16x8*)&h1[(nt * 16 + l15) * 136 + (kh * 2 + kf) * 32 + lhi * 8];

  f32x4 acc2[2][4] = {};
  const _Float16* p1 = w1c + (kh * 4 + rt) * 2048 + lane_off;

  float xmv[2][4];
  auto xmvld = [&](int m, int b) {
#pragma unroll
    for (int nt = 0; nt < 4; ++nt) xmv[b][nt] = (float)xs[xrow4[nt] + m];
  };
  auto loadA1 = [&](int m, f16x8 (&wf)[2][2]) {
    const _Float16* p = p1 + m * 16384;
    wf[0][0] = *(const f16x8*)(p);
    wf[0][1] = *(const f16x8*)(p + 512);
    wf[1][0] = *(const f16x8*)(p + 1024);
    wf[1][1] = *(const f16x8*)(p + 1536);
  };
  auto computeM = [&](f16x8 (&wf)[2][2], float (&xv)[4]) {
#pragma unroll
    for (int mt = 0; mt < 2; ++mt)
#pragma unroll
      for (int nt = 0; nt < 4; ++nt) {
        f32x4 Y = __builtin_amdgcn_mfma_f32_16x16x32_f16(wf[0][mt], hf[0][nt],
                                                         (f32x4){0.f, 0.f, 0.f, 0.f}, 0, 0, 0);
        Y = __builtin_amdgcn_mfma_f32_16x16x32_f16(wf[1][mt], hf[1][nt], Y, 0, 0, 0);
        acc2[mt][nt] += Y * xv[nt];   // v_pk_fma_f32
      }
  };

  {
    f16x8 wfA[2][2], wfB[2][2];
    loadA1(0, wfA);
    loadA1(1, wfB);
    xmvld(0, 0);
    for (int m = 0; m < 40; m += 2) {
      xmvld(m + 1, 1);
      computeM(wfA, xmv[0]);     loadA1(m + 2, wfA);   // max 41 < M1P
      if (m + 2 < 40) xmvld(m + 2, 0);
      computeM(wfB, xmv[1]);     loadA1(m + 3, wfB);
    }
  }

  // ---- combine K-halves via LDS: kh==1 writes, kh==0 adds ----
  __syncthreads();
  if (kh == 1) {
#pragma unroll
    for (int mt = 0; mt < 2; ++mt)
#pragma unroll
      for (int nt = 0; nt < 4; ++nt)
#pragma unroll
        for (int r = 0; r < 4; ++r) {
          int row = mt * 16 + lhi * 4 + r, c = nt * 16 + l15;
          red[(rt * 32 + row) * 65 + c] = acc2[mt][nt][r];
        }
  }
  __syncthreads();
  if (kh == 0) {
#pragma unroll
    for (int mt = 0; mt < 2; ++mt)
#pragma unroll
      for (int nt = 0; nt < 4; ++nt)
#pragma unroll
        for (int r = 0; r < 4; ++r) {
          int row = mt * 16 + lhi * 4 + r, c = nt * 16 + l15;
          acc2[mt][nt][r] += red[(rt * 32 + row) * 65 + c];
        }

    // ---- epilogue 1: bias+relu, d-sum -> out[ch 128..255] ----
#pragma unroll
    for (int mt = 0; mt < 2; ++mt) {
#pragma unroll
      for (int r = 0; r < 4; ++r) {
        int o = rt * 32 + mt * 16 + lhi * 4 + r;  // 0..127
        float bias = b1[o];
        float sb0 = 0.f, sb1 = 0.f;
#pragma unroll
        for (int nt = 0; nt < 4; ++nt) {
          float v = fmaxf(acc2[mt][nt][r] + bias, 0.f);
          v += __shfl_xor(v, 1); v += __shfl_xor(v, 2);
          v += __shfl_xor(v, 4); v += __shfl_xor(v, 8);
          if (nt < 2) sb0 += v; else sb1 += v;
        }
        if (l15 == 0) {
          out[(bb + 0) * 256 + 128 + o] = sb0;
          out[(bb + 1) * 256 + 128 + o] = sb1;
        }
      }
    }
  }
}

extern "C" void kernel_launch(void* const* d_in, const int* in_sizes, int n_in,
                              void* d_out, int out_size, void* d_ws, size_t ws_size,
                              hipStream_t stream) {
  const float* x  = (const float*)d_in[0];
  const float* w0 = (const float*)d_in[1];
  const float* b0 = (const float*)d_in[2];
  const float* w1 = (const float*)d_in[3];
  const float* b1 = (const float*)d_in[4];
  float* out = (float*)d_out;

  _Float16* w0n = (_Float16*)d_ws;             // 52*8192  f16 = 851968 B
  _Float16* w1c = w0n + K0P * 8192;            // 42*16384 f16 = 1376256 B

  prep_kernel<<<256, 256, 0, stream>>>(w0, w1, w0n, w1c);
  cin_kernel<<<NBLK, THREADS, 0, stream>>>(x, w0n, b0, w1c, b1, out);
}

// Round 12
// 89.136 us; speedup vs baseline: 1.3223x; 1.3223x over previous
//
#include <hip/hip_runtime.h>

// CIN (xDeepFM) fused kernel for MI355X (gfx950), round 12.
// = round 7 (86us champion) with DEEPER WEIGHT PREFETCH only:
//  - L0: 8-deep register ring af[8][2] (was 4), K0P 52->56 (branchless overrun)
//  - L1: 3-deep ring wf[3][2][2] (was 2), m-groups of 3 (39 = 13x3; the all-zero
//    m=39 step is dropped), xmv 3-slot 1-group-ahead. M1P=42 unchanged.
// Theory: ~35% no-issue cycles = waves parked on vmcnt for L2 weight loads;
// r7 vs r8/r9/r11 isolates prefetch depth as the controlling variable.

typedef _Float16 f16x8 __attribute__((ext_vector_type(8)));
typedef float f32x4 __attribute__((ext_vector_type(4)));

#define NB 2
#define NBLK 512
#define THREADS 512
#define K0P 56   // padded L0 steps (s>=50 zero weights) for 8-deep overrun
#define M1P 42   // padded L1 m (m>=39 zero weights) for 3-deep overrun

__global__ __launch_bounds__(256) void prep_kernel(
    const float* __restrict__ w0, const float* __restrict__ w1,
    _Float16* __restrict__ w0c, _Float16* __restrict__ w1c) {
  int stride = gridDim.x * blockDim.x;
  int tid = blockIdx.x * blockDim.x + threadIdx.x;
  // w0c: [s<56][w8<8][mt<2][l15<16][lhi<4][j<8]; row o=w8*32+mt*16+l15,
  // k-index ip = s*32+lhi*8+j with reorder i' = m*40+n (n<39 valid, else 0).
  const int n0 = K0P * 8192;
  for (int idx = tid; idx < n0; idx += stride) {
    int j = idx & 7, lhi = (idx >> 3) & 3, l15 = (idx >> 5) & 15;
    int mt = (idx >> 9) & 1, w8 = (idx >> 10) & 7, s = idx >> 13;
    int o = w8 * 32 + mt * 16 + l15;
    int ip = s * 32 + lhi * 8 + j;
    float v = 0.f;
    if (ip < 1560) {
      unsigned m = (unsigned)ip / 40u;
      unsigned n = (unsigned)ip - m * 40u;
      if (n < 39u) v = w0[o * 1521 + m * 39 + n];
    }
    w0c[idx] = (_Float16)v;
  }
  // w1c: [m<42][kh<2][rt<4][kf<2][mt<2][l15<16][lhi<4][j<8];
  //      row o=rt*32+mt*16+l15, k = kh*64+kf*32+lhi*8+j (within W1_m).
  const int n1 = M1P * 16384;
  for (int idx = tid; idx < n1; idx += stride) {
    int j = idx & 7, lhi = (idx >> 3) & 3, l15 = (idx >> 5) & 15;
    int mt = (idx >> 9) & 1, kf = (idx >> 10) & 1, rt = (idx >> 11) & 3;
    int kh = (idx >> 13) & 1, m = idx >> 14;
    int o = rt * 32 + mt * 16 + l15;
    int k = kh * 64 + kf * 32 + lhi * 8 + j;
    float v = (m < 39) ? w1[o * 4992 + m * 128 + k] : 0.f;
    w1c[idx] = (_Float16)v;
  }
}

__global__ __launch_bounds__(512, 2) void cin_kernel(
    const float* __restrict__ x,
    const _Float16* __restrict__ w0c, const float* __restrict__ b0,
    const _Float16* __restrict__ w1c, const float* __restrict__ b1,
    float* __restrict__ out) {
  // LDS: 5120 + 17408 + 33280 = 55808 B -> 2 blocks/CU
  __shared__ __align__(16) _Float16 xs[NB * 32 * 40];    // [c=(b,d)][40] (slot 39 = 0)
  __shared__ __align__(16) _Float16 h1[NB * 32 * 136];   // [c][136] h1a (f16)
  __shared__ __align__(16) float red[4 * 32 * 65];       // K-half exchange, row pad 65

  const int t = threadIdx.x;
  const int bb = blockIdx.x * NB;
  const int w = t >> 6;          // wave id 0..7
  const int l15 = t & 15;
  const int lhi = (t >> 4) & 3;
  const int lane_off = ((l15 << 2) | lhi) << 3;  // element offset in 1KB chunk

  int xrow[4];
#pragma unroll
  for (int nt = 0; nt < 4; ++nt) xrow[nt] = (nt * 16 + l15) * 40;

  // ---- load x[b] -> xs transposed [c][m], f16 ----
  for (int idx = t; idx < NB * 39 * 32; idx += THREADS) {
    int b = idx / 1248; int rem = idx - b * 1248;
    int m = rem >> 5; int d = rem & 31;
    xs[(b * 32 + d) * 40 + m] = (_Float16)x[(bb + b) * 1248 + rem];
  }
  if (t < NB * 32) xs[t * 40 + 39] = (_Float16)0.f;  // zero the m=39 pad
  __syncthreads();

  // ================= LAYER 0 (barrier-free, 8-deep weight ring) =================
  f32x4 acc[2][4] = {};
  const _Float16* p0 = w0c + w * 1024 + lane_off;

  f16x8 af[8][2];
  auto loadA0 = [&](int s, int q) {
    const _Float16* p = p0 + s * 8192;
    af[q][0] = *(const f16x8*)(p);
    af[q][1] = *(const f16x8*)(p + 512);
  };
  auto zfr = [&](int s, f16x8 (&bz)[4]) {
    unsigned i0 = (unsigned)(s * 32) + (unsigned)lhi * 8u;
    unsigned m = (i0 * 52429u) >> 21;   // i0/40 (exact for i0 < 2^16)
    unsigned nb = i0 - m * 40u;
#pragma unroll
    for (int nt = 0; nt < 4; ++nt) {
      _Float16 xm = xs[xrow[nt] + m];                 // m==39 -> 0
      f16x8 xn = *(const f16x8*)&xs[xrow[nt] + nb];   // 16B-aligned (80B rows)
      bz[nt] = xn * xm;                               // v_pk_mul_f16
    }
  };
  auto comp0 = [&](int q, f16x8 (&bz)[4]) {
#pragma unroll
    for (int mt = 0; mt < 2; ++mt)
#pragma unroll
      for (int nt = 0; nt < 4; ++nt)
        acc[mt][nt] = __builtin_amdgcn_mfma_f32_16x16x32_f16(af[q][mt], bz[nt], acc[mt][nt], 0, 0, 0);
  };

  {
#pragma unroll
    for (int q = 0; q < 8; ++q) loadA0(q, q);
    for (int s = 0; s < 48; s += 8) {
#pragma unroll
      for (int q = 0; q < 8; ++q) {
        f16x8 bz[4];
        zfr(s + q, bz);
        comp0(q, bz);
        loadA0(s + q + 8, q);   // max 55 < K0P
      }
    }
    f16x8 bz[4];
    zfr(48, bz); comp0(0, bz);
    zfr(49, bz); comp0(1, bz);
  }

  // ---- epilogue 0: bias+relu; o<128 -> h1a LDS; o>=128 -> d-sum -> out[ch 0..127]
  if (w < 4) {
#pragma unroll
    for (int mt = 0; mt < 2; ++mt) {
#pragma unroll
      for (int nt = 0; nt < 4; ++nt) {
        int c = nt * 16 + l15;
        int hbase = c * 136;
#pragma unroll
        for (int r = 0; r < 4; ++r) {
          int o = w * 32 + mt * 16 + lhi * 4 + r;
          float v = fmaxf(acc[mt][nt][r] + b0[o], 0.f);
          h1[hbase + o] = (_Float16)v;
        }
      }
    }
  } else {
#pragma unroll
    for (int mt = 0; mt < 2; ++mt) {
#pragma unroll
      for (int r = 0; r < 4; ++r) {
        int o = w * 32 + mt * 16 + lhi * 4 + r;  // 128..255
        float bias = b0[o];
        float sb0 = 0.f, sb1 = 0.f;
#pragma unroll
        for (int nt = 0; nt < 4; ++nt) {
          float v = fmaxf(acc[mt][nt][r] + bias, 0.f);
          v += __shfl_xor(v, 1); v += __shfl_xor(v, 2);
          v += __shfl_xor(v, 4); v += __shfl_xor(v, 8);
          if (nt < 2) sb0 += v; else sb1 += v;
        }
        if (l15 == 0) {
          out[(bb + 0) * 256 + (o - 128)] = sb0;
          out[(bb + 1) * 256 + (o - 128)] = sb1;
        }
      }
    }
  }
  __syncthreads();  // h1a visible to all waves

  // ============ LAYER 1 (reassociated; 4 row-groups x 2 K-halves; 3-deep) ============
  const int rt = w >> 1;   // row group: rows rt*32 .. rt*32+31
  const int kh = w & 1;    // K half: k in [kh*64, kh*64+64)

  // hf[kf][nt]: persistent B fragments of h for this K-half (32 VGPRs)
  f16x8 hf[2][4];
#pragma unroll
  for (int kf = 0; kf < 2; ++kf)
#pragma unroll
    for (int nt = 0; nt < 4; ++nt)
      hf[kf][nt] = *(const f16x8*)&h1[(nt * 16 + l15) * 136 + (kh * 2 + kf) * 32 + lhi * 8];

  f32x4 acc2[2][4] = {};
  const _Float16* p1 = w1c + (kh * 4 + rt) * 2048 + lane_off;

  f16x8 wf[3][2][2];
  auto loadA1 = [&](int m, int q) {
    const _Float16* p = p1 + m * 16384;
    wf[q][0][0] = *(const f16x8*)(p);
    wf[q][0][1] = *(const f16x8*)(p + 512);
    wf[q][1][0] = *(const f16x8*)(p + 1024);
    wf[q][1][1] = *(const f16x8*)(p + 1536);
  };
  float xmv[3][4];
  auto xmvld = [&](int m, int q) {
#pragma unroll
    for (int nt = 0; nt < 4; ++nt) xmv[q][nt] = (float)xs[xrow[nt] + m];
  };
  auto computeM = [&](int q, float (&xv)[4]) {
#pragma unroll
    for (int mt = 0; mt < 2; ++mt)
#pragma unroll
      for (int nt = 0; nt < 4; ++nt) {
        f32x4 Y = __builtin_amdgcn_mfma_f32_16x16x32_f16(wf[q][0][mt], hf[0][nt],
                                                         (f32x4){0.f, 0.f, 0.f, 0.f}, 0, 0, 0);
        Y = __builtin_amdgcn_mfma_f32_16x16x32_f16(wf[q][1][mt], hf[1][nt], Y, 0, 0, 0);
        acc2[mt][nt] += Y * xv[nt];   // v_pk_fma_f32
      }
  };

  {
    loadA1(0, 0); loadA1(1, 1); loadA1(2, 2);
    xmvld(0, 0); xmvld(1, 1); xmvld(2, 2);
#pragma unroll
    for (int m = 0; m < 39; m += 3) {     // 13 groups; m=39 (zero) skipped
      computeM(0, xmv[0]); loadA1(m + 3, 0);   // max 39 < M1P
      if (m + 3 < 39) xmvld(m + 3, 0);
      computeM(1, xmv[1]); loadA1(m + 4, 1);   // max 40 < M1P
      if (m + 4 < 39) xmvld(m + 4, 1);
      computeM(2, xmv[2]); loadA1(m + 5, 2);   // max 41 < M1P
      if (m + 5 < 39) xmvld(m + 5, 2);
    }
  }

  // ---- combine K-halves via LDS: kh==1 writes, kh==0 adds ----
  __syncthreads();
  if (kh == 1) {
#pragma unroll
    for (int mt = 0; mt < 2; ++mt)
#pragma unroll
      for (int nt = 0; nt < 4; ++nt)
#pragma unroll
        for (int r = 0; r < 4; ++r) {
          int row = mt * 16 + lhi * 4 + r, c = nt * 16 + l15;
          red[(rt * 32 + row) * 65 + c] = acc2[mt][nt][r];
        }
  }
  __syncthreads();
  if (kh == 0) {
#pragma unroll
    for (int mt = 0; mt < 2; ++mt)
#pragma unroll
      for (int nt = 0; nt < 4; ++nt)
#pragma unroll
        for (int r = 0; r < 4; ++r) {
          int row = mt * 16 + lhi * 4 + r, c = nt * 16 + l15;
          acc2[mt][nt][r] += red[(rt * 32 + row) * 65 + c];
        }

    // ---- epilogue 1: bias+relu, d-sum -> out[ch 128..255]
#pragma unroll
    for (int mt = 0; mt < 2; ++mt) {
#pragma unroll
      for (int r = 0; r < 4; ++r) {
        int o = rt * 32 + mt * 16 + lhi * 4 + r;  // 0..127
        float bias = b1[o];
        float sb0 = 0.f, sb1 = 0.f;
#pragma unroll
        for (int nt = 0; nt < 4; ++nt) {
          float v = fmaxf(acc2[mt][nt][r] + bias, 0.f);
          v += __shfl_xor(v, 1); v += __shfl_xor(v, 2);
          v += __shfl_xor(v, 4); v += __shfl_xor(v, 8);
          if (nt < 2) sb0 += v; else sb1 += v;
        }
        if (l15 == 0) {
          out[(bb + 0) * 256 + 128 + o] = sb0;
          out[(bb + 1) * 256 + 128 + o] = sb1;
        }
      }
    }
  }
}

extern "C" void kernel_launch(void* const* d_in, const int* in_sizes, int n_in,
                              void* d_out, int out_size, void* d_ws, size_t ws_size,
                              hipStream_t stream) {
  const float* x  = (const float*)d_in[0];
  const float* w0 = (const float*)d_in[1];
  const float* b0 = (const float*)d_in[2];
  const float* w1 = (const float*)d_in[3];
  const float* b1 = (const float*)d_in[4];
  float* out = (float*)d_out;

  _Float16* w0c = (_Float16*)d_ws;             // 56*8192  f16 = 917504 B
  _Float16* w1c = w0c + K0P * 8192;            // 42*16384 f16 = 1376256 B

  prep_kernel<<<256, 256, 0, stream>>>(w0, w1, w0c, w1c);
  cin_kernel<<<NBLK, THREADS, 0, stream>>>(x, w0c, b0, w1c, b1, out);
}